// Round 11
// baseline (552.114 us; speedup 1.0000x reference)
//
#include <hip/hip_runtime.h>

// ---------------------------------------------------------------------------
// TPAttention: fp16x3-split MFMA GEMMs + fp16 MFMA flash attention.
//  gemm16 v2: 128x128 tile, BK=64, wave-tile 64x64 (frags 4x4), ratio-3.
//  attn_mfma unchanged (validated round 10: 116us, 0 bank conflicts).
// ---------------------------------------------------------------------------

typedef _Float16 f16;
typedef _Float16 f16x8 __attribute__((ext_vector_type(8)));
typedef _Float16 f16x4 __attribute__((ext_vector_type(4)));
typedef float f32x4 __attribute__((ext_vector_type(4)));

#define N_HEADS 16
#define D_KV 64
#define QLEN 1024
#define BS 4
#define DMODEL 1024
#define NROWS (BS * QLEN)   // 4096
#define KDIM 1024

__device__ __forceinline__ void ldsload16(const void* g, void* l) {
  __builtin_amdgcn_global_load_lds(
      (const __attribute__((address_space(1))) void*)g,
      (__attribute__((address_space(3))) void*)l, 16, 0, 0);
}

// ============================ bias table ====================================
__global__ void build_bias_tab(const float* __restrict__ rel_bias,
                               float* __restrict__ tab) {
  int idx = blockIdx.x * 256 + threadIdx.x;   // [0, 16*2047)
  if (idx >= 16 * 2047) return;
  int h = idx / 2047;
  int rel = idx % 2047 - 1023;                // rel = k - q
  int n = -rel;
  int ret = 0;
  if (n < 0) { ret = 16; n = -n; }
  int b;
  if (n < 8) {
    b = n;
  } else {
    int e  = 31 - __builtin_clz((unsigned)n);
    int f2 = 2 * e + ((n * n >= (1 << (2 * e + 1))) ? 1 : 0);
    int val = f2 - 6 + 8;
    b = val > 15 ? 15 : val;
  }
  b += ret;
  tab[idx] = rel_bias[b * 16 + h];
}

// ============================ R normalization ===============================
__global__ void normalize_R(const float* __restrict__ R, float* __restrict__ RM) {
  int r = blockIdx.x;
  int d = threadIdx.x;
  float v = R[r * 64 + d];
  float ss = v * v;
  #pragma unroll
  for (int o = 32; o; o >>= 1) ss += __shfl_xor(ss, o);
  RM[r * 64 + d] = v / sqrtf(ss);
}

// ============================ fp32 -> hi/lo fp16 split ======================
__global__ __launch_bounds__(256) void split_rows(
    const float* __restrict__ X, f16* __restrict__ Hi, f16* __restrict__ Lo) {
  size_t i = ((size_t)blockIdx.x * 256 + threadIdx.x) * 8;
  float4 v0 = *(const float4*)(X + i);
  float4 v1 = *(const float4*)(X + i + 4);
  float xs[8] = {v0.x, v0.y, v0.z, v0.w, v1.x, v1.y, v1.z, v1.w};
  f16x8 h8, l8;
  #pragma unroll
  for (int j = 0; j < 8; ++j) {
    f16 h = (f16)xs[j];
    h8[j] = h;
    l8[j] = (f16)(xs[j] - (float)h);
  }
  *(f16x8*)(Hi + i) = h8;
  *(f16x8*)(Lo + i) = l8;
}

// ============== W[K][N] f32 -> WT hi/lo fp16 [N][K] (64x64 tiles) ===========
__global__ __launch_bounds__(256) void transpose_split(
    const float* __restrict__ W, f16* __restrict__ Thi, f16* __restrict__ Tlo) {
  __shared__ float tile[64][65];
  int tid = threadIdx.x;
  int n0 = (blockIdx.x & 15) * 64, k0 = (blockIdx.x >> 4) * 64;
  #pragma unroll
  for (int it = 0; it < 16; ++it) {
    int idx = it * 256 + tid;
    int r = idx >> 6, c = idx & 63;
    tile[r][c] = W[(size_t)(k0 + r) * DMODEL + n0 + c];
  }
  __syncthreads();
  #pragma unroll
  for (int it = 0; it < 16; ++it) {
    int idx = it * 256 + tid;
    int rr = idx >> 6, cc = idx & 63;
    float x = tile[cc][rr];
    f16 hv = (f16)x;
    size_t o = (size_t)(n0 + rr) * KDIM + k0 + cc;
    Thi[o] = hv;
    Tlo[o] = (f16)(x - (float)hv);
  }
}

// ============================ fp16x3 MFMA GEMM v2 ===========================
// C[4096][1024] = (Ahi+Alo)[M][K] @ (Bhi+Blo)^T, B given as [N][K].
// Tile 128x128, BK=64 (2x 32-K panels), 4 waves 2x2, wave-tile 64x64,
// frags 4x4, 3-term split => 96 MFMA / 32 ds_read_b128 per wave per K-step.
// LDS 64KB. Grid (N/128, M/128) = (8, 32) = 256 blocks.
// EPI 0: f32 [M][1024].  EPI 2: f32 + bias.
// EPI 1: hi/lo f16 scatter to [b,h,s,d].
// EPI 3: hi f16 scatter TRANSPOSED to [b,h,d,s] (packed 4-wide in s).
#define GBM 128
#define GBN 128
#define GBK 64
template<int EPI>
__global__ __launch_bounds__(256) void gemm16(
    const f16* __restrict__ Ahi, const f16* __restrict__ Alo,
    const f16* __restrict__ Bhi, const f16* __restrict__ Blo,
    const float* __restrict__ bias, float* __restrict__ C,
    f16* __restrict__ Ch, f16* __restrict__ Cl) {
  // per 32-K panel: AHI 8x1KB | ALO 8x1KB | BHI 8x1KB | BLO 8x1KB = 32KB
  __shared__ __align__(16) char smem[64 * 1024];

  const int tid = threadIdx.x;
  const int lane = tid & 63, wid = tid >> 6;
  const int wr = wid >> 1, wc = wid & 1;
  const int row0 = blockIdx.y * GBM, col0 = blockIdx.x * GBN;
  const int lr = lane & 15, lk = (lane >> 4) << 3;

  // per-lane global offsets (f16 element units); groups g: A rows row0+g*16,
  // B rows (of WT [N][K]) col0+g*16. Wave w stages groups {w, w+4}.
  const size_t aoff0 = (size_t)(row0 + wid * 16 + lr) * KDIM + lk;
  const size_t aoff1 = (size_t)(row0 + (wid + 4) * 16 + lr) * KDIM + lk;
  const size_t boff0 = (size_t)(col0 + wid * 16 + lr) * KDIM + lk;
  const size_t boff1 = (size_t)(col0 + (wid + 4) * 16 + lr) * KDIM + lk;

  f32x4 acc[4][4] = {};

  for (int k0 = 0; k0 < KDIM; k0 += GBK) {
    #pragma unroll
    for (int ks = 0; ks < 2; ++ks) {
      char* P = smem + ks * 32768;
      int kk = k0 + ks * 32;
      ldsload16(Ahi + aoff0 + kk, P + wid * 1024);
      ldsload16(Ahi + aoff1 + kk, P + (wid + 4) * 1024);
      ldsload16(Alo + aoff0 + kk, P + 8192 + wid * 1024);
      ldsload16(Alo + aoff1 + kk, P + 8192 + (wid + 4) * 1024);
      ldsload16(Bhi + boff0 + kk, P + 16384 + wid * 1024);
      ldsload16(Bhi + boff1 + kk, P + 16384 + (wid + 4) * 1024);
      ldsload16(Blo + boff0 + kk, P + 24576 + wid * 1024);
      ldsload16(Blo + boff1 + kk, P + 24576 + (wid + 4) * 1024);
    }
    __syncthreads();   // drains vmcnt (global_load_lds) + barrier

    #pragma unroll
    for (int ks = 0; ks < 2; ++ks) {
      char* P = smem + ks * 32768;
      f16x8 ah[4], al[4], bh[4], bl[4];
      #pragma unroll
      for (int mi = 0; mi < 4; ++mi) {
        ah[mi] = *(const f16x8*)(P + (wr * 4 + mi) * 1024 + lane * 16);
        al[mi] = *(const f16x8*)(P + 8192 + (wr * 4 + mi) * 1024 + lane * 16);
      }
      #pragma unroll
      for (int ni = 0; ni < 4; ++ni) {
        bh[ni] = *(const f16x8*)(P + 16384 + (wc * 4 + ni) * 1024 + lane * 16);
        bl[ni] = *(const f16x8*)(P + 24576 + (wc * 4 + ni) * 1024 + lane * 16);
      }
      #pragma unroll
      for (int mi = 0; mi < 4; ++mi)
        #pragma unroll
        for (int ni = 0; ni < 4; ++ni) {
          acc[mi][ni] = __builtin_amdgcn_mfma_f32_16x16x32_f16(ah[mi], bh[ni], acc[mi][ni], 0, 0, 0);
          acc[mi][ni] = __builtin_amdgcn_mfma_f32_16x16x32_f16(al[mi], bh[ni], acc[mi][ni], 0, 0, 0);
          acc[mi][ni] = __builtin_amdgcn_mfma_f32_16x16x32_f16(ah[mi], bl[ni], acc[mi][ni], 0, 0, 0);
        }
    }
    __syncthreads();   // all reads done before next stage overwrites
  }

  // epilogue: C/D frag mapping col = lane&15, row = (lane>>4)*4 + reg
  #pragma unroll
  for (int mi = 0; mi < 4; ++mi) {
    #pragma unroll
    for (int ni = 0; ni < 4; ++ni) {
      int c = col0 + wc * 64 + ni * 16 + lr;
      int rbase = row0 + wr * 64 + mi * 16 + (lane >> 4) * 4;
      if (EPI == 3) {
        // transposed hi-only: [b,h,d,s], 4 consecutive s packed
        int b_ = rbase >> 10, s0 = rbase & 1023, h = c >> 6, d = c & 63;
        f16x4 hv;
        #pragma unroll
        for (int r = 0; r < 4; ++r) hv[r] = (f16)acc[mi][ni][r];
        *(f16x4*)(Ch + ((size_t)(b_ * 16 + h) << 16) + d * 1024 + s0) = hv;
      } else {
        #pragma unroll
        for (int r = 0; r < 4; ++r) {
          int rr = rbase + r;
          float v = acc[mi][ni][r];
          if (EPI == 2) v += bias[c];
          if (EPI == 1) {
            int b_ = rr >> 10, s = rr & 1023, h = c >> 6, d = c & 63;
            size_t o = ((size_t)(b_ * 16 + h) << 16) + (s << 6) + d;
            f16 hv = (f16)v;
            Ch[o] = hv;
            Cl[o] = (f16)(v - (float)hv);
          } else {
            C[(size_t)rr * DMODEL + c] = v;
          }
        }
      }
    }
  }
}

// ============================ MFMA flash attention ==========================
// (unchanged from round 10: 116us, 0 bank conflicts, verified)
__global__ __launch_bounds__(256) void attn_mfma(
    const f16* __restrict__ Qh, const f16* __restrict__ Ql,
    const f16* __restrict__ Kh, const f16* __restrict__ Kl,
    const f16* __restrict__ Vt, const float* __restrict__ tab2,
    f16* __restrict__ vb_hi, f16* __restrict__ vb_lo) {
  __shared__ __align__(16) char sm[40 * 1024];
  char* KH = sm;              // 8KB: (ni*2+kb)*1024, frag-major
  char* KL = sm + 8192;       // 8KB
  char* VH = sm + 16384;      // 8KB: (nd*2+kb)*1024
  char* PH = sm + 24576;      // 8KB: per-wave 2KB, [q][k] swizzled
  char* PL = sm + 32768;      // 8KB

  const int tid = threadIdx.x;
  const int l = tid & 63, w = tid >> 6;
  const int lr = l & 15, lg = l >> 4;
  const int bh = blockIdx.y, h = bh & 15;
  const int q0 = blockIdx.x * 64;
  const size_t base = (size_t)bh << 16;

  const size_t qrow = base + (size_t)(q0 + w * 16 + lr) * 64 + lg * 8;
  f16x8 qh[2], ql[2];
  qh[0] = *(const f16x8*)(Qh + qrow);
  qh[1] = *(const f16x8*)(Qh + qrow + 32);
  ql[0] = *(const f16x8*)(Ql + qrow);
  ql[1] = *(const f16x8*)(Ql + qrow + 32);

  float m_run[4] = {-1e30f, -1e30f, -1e30f, -1e30f};
  float l_run[4] = {};
  f32x4 o4[4] = {};
  const int bconst = h * 2047 + 1023 - (q0 + w * 16 + lg * 4);

  for (int k0 = 0; k0 < QLEN; k0 += 64) {
    {
      const f16* ks = Kh + base + (size_t)(k0 + w * 16 + lr) * 64 + lg * 8;
      ldsload16(ks,      KH + (w * 2 + 0) * 1024);
      ldsload16(ks + 32, KH + (w * 2 + 1) * 1024);
      const f16* ks2 = Kl + base + (size_t)(k0 + w * 16 + lr) * 64 + lg * 8;
      ldsload16(ks2,      KL + (w * 2 + 0) * 1024);
      ldsload16(ks2 + 32, KL + (w * 2 + 1) * 1024);
      const f16* vs = Vt + base + (size_t)(w * 16 + lr) * 1024 + k0 + lg * 8;
      ldsload16(vs,      VH + (w * 2 + 0) * 1024);
      ldsload16(vs + 32, VH + (w * 2 + 1) * 1024);
    }
    __syncthreads();

    f32x4 s4[4];
    #pragma unroll
    for (int ni = 0; ni < 4; ++ni) {
      f16x8 kh0 = *(const f16x8*)(KH + (ni * 2 + 0) * 1024 + l * 16);
      f16x8 kh1 = *(const f16x8*)(KH + (ni * 2 + 1) * 1024 + l * 16);
      f16x8 kl0 = *(const f16x8*)(KL + (ni * 2 + 0) * 1024 + l * 16);
      f16x8 kl1 = *(const f16x8*)(KL + (ni * 2 + 1) * 1024 + l * 16);
      f32x4 a = {};
      a = __builtin_amdgcn_mfma_f32_16x16x32_f16(qh[0], kh0, a, 0, 0, 0);
      a = __builtin_amdgcn_mfma_f32_16x16x32_f16(qh[1], kh1, a, 0, 0, 0);
      a = __builtin_amdgcn_mfma_f32_16x16x32_f16(ql[0], kh0, a, 0, 0, 0);
      a = __builtin_amdgcn_mfma_f32_16x16x32_f16(ql[1], kh1, a, 0, 0, 0);
      a = __builtin_amdgcn_mfma_f32_16x16x32_f16(qh[0], kl0, a, 0, 0, 0);
      a = __builtin_amdgcn_mfma_f32_16x16x32_f16(qh[1], kl1, a, 0, 0, 0);
      s4[ni] = a;
    }
    #pragma unroll
    for (int ni = 0; ni < 4; ++ni)
      #pragma unroll
      for (int r = 0; r < 4; ++r)
        s4[ni][r] += tab2[bconst + (k0 + ni * 16 + lr) - r];

    float m_new[4], scl[4], rs[4];
    #pragma unroll
    for (int r = 0; r < 4; ++r) {
      float m = fmaxf(fmaxf(s4[0][r], s4[1][r]), fmaxf(s4[2][r], s4[3][r]));
      #pragma unroll
      for (int off = 1; off < 16; off <<= 1) m = fmaxf(m, __shfl_xor(m, off));
      m_new[r] = fmaxf(m_run[r], m);
      scl[r] = __expf(m_run[r] - m_new[r]);
      m_run[r] = m_new[r];
      rs[r] = 0.f;
    }
    #pragma unroll
    for (int ni = 0; ni < 4; ++ni) {
      #pragma unroll
      for (int r = 0; r < 4; ++r) {
        float p = __expf(s4[ni][r] - m_new[r]);
        rs[r] += p;
        f16 ph = (f16)p;
        f16 pl = (f16)(p - (float)ph);
        int qq = lg * 4 + r, kk = ni * 16 + lr;
        int off = w * 2048 + qq * 128 + ((kk * 2) ^ ((qq & 7) << 4));
        *(f16*)(PH + off) = ph;
        *(f16*)(PL + off) = pl;
      }
    }
    #pragma unroll
    for (int r = 0; r < 4; ++r) {
      float s = rs[r];
      #pragma unroll
      for (int off = 1; off < 16; off <<= 1) s += __shfl_xor(s, off);
      l_run[r] = l_run[r] * scl[r] + s;
    }
    #pragma unroll
    for (int nd = 0; nd < 4; ++nd)
      #pragma unroll
      for (int r = 0; r < 4; ++r) o4[nd][r] *= scl[r];

    const int poff0 = w * 2048 + lr * 128 + ((lg * 16) ^ ((lr & 7) << 4));
    const int poff1 = w * 2048 + lr * 128 + ((64 + lg * 16) ^ ((lr & 7) << 4));
    f16x8 pah0 = *(const f16x8*)(PH + poff0);
    f16x8 pah1 = *(const f16x8*)(PH + poff1);
    f16x8 pal0 = *(const f16x8*)(PL + poff0);
    f16x8 pal1 = *(const f16x8*)(PL + poff1);
    #pragma unroll
    for (int nd = 0; nd < 4; ++nd) {
      f16x8 vh0 = *(const f16x8*)(VH + (nd * 2 + 0) * 1024 + l * 16);
      f16x8 vh1 = *(const f16x8*)(VH + (nd * 2 + 1) * 1024 + l * 16);
      o4[nd] = __builtin_amdgcn_mfma_f32_16x16x32_f16(pah0, vh0, o4[nd], 0, 0, 0);
      o4[nd] = __builtin_amdgcn_mfma_f32_16x16x32_f16(pah1, vh1, o4[nd], 0, 0, 0);
      o4[nd] = __builtin_amdgcn_mfma_f32_16x16x32_f16(pal0, vh0, o4[nd], 0, 0, 0);
      o4[nd] = __builtin_amdgcn_mfma_f32_16x16x32_f16(pal1, vh1, o4[nd], 0, 0, 0);
    }
    __syncthreads();
  }

  const int b_ = bh >> 4;
  #pragma unroll
  for (int r = 0; r < 4; ++r) {
    float inv = 1.f / l_run[r];
    int q = q0 + w * 16 + lg * 4 + r;
    size_t rowb = ((size_t)(b_ * 1024 + q) << 10) + h * 64;
    #pragma unroll
    for (int nd = 0; nd < 4; ++nd) {
      float x = o4[nd][r] * inv;
      f16 hv = (f16)x;
      vb_hi[rowb + nd * 16 + lr] = hv;
      vb_lo[rowb + nd * 16 + lr] = (f16)(x - (float)hv);
    }
  }
}

// ============================ role binding ==================================
__global__ __launch_bounds__(256) void role_bind(
    const float* __restrict__ role_scores, const float* __restrict__ RM,
    const f16* __restrict__ Vhi, const f16* __restrict__ Vlo,
    f16* __restrict__ Bhi, f16* __restrict__ Blo) {
  __shared__ float rm[64][64];
  int tid = threadIdx.x;
  #pragma unroll
  for (int p = 0; p < 4; ++p) {
    int idx = tid + p * 256;
    ((float4*)rm)[idx] = ((const float4*)RM)[idx];
  }
  __syncthreads();
  int wave = tid >> 6, lane = tid & 63;
  #pragma unroll
  for (int i = 0; i < 4; ++i) {
    int row = blockIdx.x * 16 + wave * 4 + i;
    int bq = row >> 4, h = row & 15;
    float s = role_scores[((size_t)bq << 10) + h * 64 + lane];
    float m = s;
    #pragma unroll
    for (int o = 32; o; o >>= 1) m = fmaxf(m, __shfl_xor(m, o));
    float e = expf(s - m);
    float l = e;
    #pragma unroll
    for (int o = 32; o; o >>= 1) l += __shfl_xor(l, o);
    float a = e / l;
    float rd = 0.f;
    #pragma unroll
    for (int r = 0; r < 64; ++r) rd += __shfl(a, r) * rm[r][lane];
    size_t idx = ((size_t)bq << 10) + h * 64 + lane;
    float vb = (float)Vhi[idx] + (float)Vlo[idx];
    float x = vb * rd;
    f16 hv = (f16)x;
    Bhi[idx] = hv;
    Blo[idx] = (f16)(x - (float)hv);
  }
}

// ============================ launcher ======================================
extern "C" void kernel_launch(void* const* d_in, const int* in_sizes, int n_in,
                              void* d_out, int out_size, void* d_ws, size_t ws_size,
                              hipStream_t stream) {
  const float* input    = (const float*)d_in[0];
  const float* Wq       = (const float*)d_in[1];
  const float* Wk       = (const float*)d_in[2];
  const float* Wv       = (const float*)d_in[3];
  const float* Wo       = (const float*)d_in[4];
  const float* Wr       = (const float*)d_in[5];
  const float* br       = (const float*)d_in[6];
  const float* R        = (const float*)d_in[7];
  const float* rel_bias = (const float*)d_in[8];

  char* W = (char*)d_ws;
  const size_t MB84 = 8388608;   // one f16 [b,h,s,d] buffer
  f16*   Qh    = (f16*)(W);                  // dead after attn -> wt2
  f16*   Qlo   = (f16*)(W + MB84);           // dead after attn -> bd_hi
  f16*   Khh   = (f16*)(W + 2 * MB84);       // dead after attn -> rs (f32, 2 slots)
  f16*   Kll   = (f16*)(W + 3 * MB84);
  f16*   Vtt   = (f16*)(W + 4 * MB84);       // dead after attn -> bd_lo
  f16*   vb_hi = (f16*)(W + 5 * MB84);       // wt/wt3 slot before/after its lifetime
  f16*   vb_lo = (f16*)(W + 6 * MB84);
  float* tab2  = (float*)(W + 7 * MB84);     // 16*2047*4 = 131008 B
  float* rm_ws = (float*)(W + 7 * MB84 + 131072);   // 16 KB

  f16* in_hi = (f16*)d_out;                  // d_out scratch, dead before final gemm
  f16* in_lo = in_hi + 4194304;
  f16* wt_hi = vb_hi;                        // 2MB each, inside vb slot (pre-attn)
  f16* wt_lo = wt_hi + 1048576;
  f16* wt2_hi = Qh;                          // post-attn slots
  f16* wt2_lo = wt2_hi + 1048576;
  float* rs_ws = (float*)(W + 2 * MB84);     // 16MB over Kh+Kl
  f16* bd_hi = Qlo;
  f16* bd_lo = Vtt;
  f16* wt3_hi = vb_hi;                       // after role_bind, vb dead
  f16* wt3_lo = wt3_hi + 1048576;

  build_bias_tab<<<128, 256, 0, stream>>>(rel_bias, tab2);
  normalize_R<<<64, 64, 0, stream>>>(R, rm_ws);
  split_rows<<<2048, 256, 0, stream>>>(input, in_hi, in_lo);

  dim3 gg(DMODEL / GBN, NROWS / GBM);        // (8, 32) = 256 blocks
  transpose_split<<<256, 256, 0, stream>>>(Wq, wt_hi, wt_lo);
  gemm16<1><<<gg, 256, 0, stream>>>(in_hi, in_lo, wt_hi, wt_lo, nullptr, nullptr, Qh, Qlo);
  transpose_split<<<256, 256, 0, stream>>>(Wk, wt_hi, wt_lo);
  gemm16<1><<<gg, 256, 0, stream>>>(in_hi, in_lo, wt_hi, wt_lo, nullptr, nullptr, Khh, Kll);
  transpose_split<<<256, 256, 0, stream>>>(Wv, wt_hi, wt_lo);
  gemm16<3><<<gg, 256, 0, stream>>>(in_hi, in_lo, wt_hi, wt_lo, nullptr, nullptr, Vtt, nullptr);

  attn_mfma<<<dim3(QLEN / 64, BS * N_HEADS), 256, 0, stream>>>(
      Qh, Qlo, Khh, Kll, Vtt, tab2, vb_hi, vb_lo);

  transpose_split<<<256, 256, 0, stream>>>(Wr, wt2_hi, wt2_lo);
  gemm16<2><<<gg, 256, 0, stream>>>(vb_hi, vb_lo, wt2_hi, wt2_lo, br, rs_ws, nullptr, nullptr);
  role_bind<<<4096, 256, 0, stream>>>(rs_ws, rm_ws, vb_hi, vb_lo, bd_hi, bd_lo);
  transpose_split<<<256, 256, 0, stream>>>(Wo, wt3_hi, wt3_lo);
  gemm16<0><<<gg, 256, 0, stream>>>(bd_hi, bd_lo, wt3_hi, wt3_lo, nullptr, (float*)d_out, nullptr, nullptr);
}